// Round 1
// baseline (3324.820 us; speedup 1.0000x reference)
//
#include <hip/hip_runtime.h>
#include <hip/hip_bf16.h>

// Problem constants (Point_Transformer_Last): B=16, C=256, N=2048, NUM_SA=4
static constexpr int Bn = 16;
static constexpr int Cc = 256;
static constexpr int Nn = 2048;
static constexpr int C4 = 64;   // C/4

#define DEVI __device__ __forceinline__

DEVI float bf2f(unsigned short u) { return __uint_as_float(((unsigned)u) << 16); }
DEVI unsigned short f2bf(float f) {
    unsigned x = __float_as_uint(f);
    x += 0x7fffu + ((x >> 16) & 1u);   // RNE
    return (unsigned short)(x >> 16);
}

enum { M_NONE = 0, M_EOUT = 1, M_BIAS = 2, M_BNRELU = 3, M_XR = 4, M_TOUT = 5 };

// Generic fp32 GEMM: Y[b,i,j] = epilogue( sum_k A(b,i,k) * B(b,k,j) )
//  - A row-major [M,K] (lda=K) or, if ATRANS, stored [K,*] with lda = m-stride (energy: A=q).
//  - B row-major [K,N] fp32, or bf16 (ushort) if BBF16.
//  - 128x128x16 tile, 256 threads, 8x8 per-thread micro-tile.
// Epilogues:
//  M_NONE   : raw fp32 store (q)
//  M_EOUT   : bf16 store (energy logits)
//  M_BIAS   : + bias[i] (xv)
//  M_BNRELU : relu(bn(acc)) (conv1/conv2)
//  M_XR     : Y = Haux - acc/(1e-9+colsum[j])   (d = h - x_r, colsum normalization folded in)
//  M_TOUT   : Y = Haux + relu(bn(acc + bias[i])) (SA layer output)
template<int MODE, bool ATRANS, bool BBF16>
__global__ __launch_bounds__(256)
void gemm_kernel(const float* __restrict__ A, long aBatch, int lda,
                 const void* __restrict__ Bv, long bBatch,
                 void* __restrict__ Yv, long yBatch,
                 const float* __restrict__ Haux, long hBatch,
                 const float* __restrict__ bias,
                 const float* __restrict__ bng, const float* __restrict__ bnb,
                 const float* __restrict__ bnm, const float* __restrict__ bnv,
                 const float* __restrict__ colsum,
                 int M, int N, int K)
{
    constexpr int BM = 128, BN = 128, BK = 16;
    __shared__ float As[BK][BM + 4];   // row stride 132 floats = 528B (16B aligned)
    __shared__ float Bs[BK][BN + 4];

    const int tid = threadIdx.x;
    const int b   = blockIdx.z;
    const int n0  = blockIdx.x * BN;
    const int m0  = blockIdx.y * BM;
    const float* Ab = A + (long)b * aBatch;

    float acc[8][8];
    #pragma unroll
    for (int i = 0; i < 8; ++i)
        #pragma unroll
        for (int j = 0; j < 8; ++j) acc[i][j] = 0.f;

    const int tx = tid & 15, ty = tid >> 4;

    for (int k0 = 0; k0 < K; k0 += BK) {
        if (ATRANS) {
            // As[kk][mm] = A[(k0+kk)*lda + m0+mm]  (contiguous in m -> float4)
            const int kk = tid >> 5;            // 0..7
            const int m4 = (tid & 31) << 2;     // 0..124
            #pragma unroll
            for (int r = 0; r < 2; ++r) {
                const float* src = Ab + (long)(k0 + kk + 8 * r) * lda + (m0 + m4);
                *(float4*)&As[kk + 8 * r][m4] = *(const float4*)src;
            }
        } else {
            // As[kk][mm] = A[(m0+mm)*lda + k0+kk]  (load float4 along k, transpose into LDS)
            const int rr = tid >> 2;            // 0..63
            const int c4 = (tid & 3) << 2;      // 0,4,8,12
            #pragma unroll
            for (int r = 0; r < 2; ++r) {
                const int mm = rr + 64 * r;
                float4 v = make_float4(0.f, 0.f, 0.f, 0.f);
                if (m0 + mm < M)
                    v = *(const float4*)(Ab + (long)(m0 + mm) * lda + (k0 + c4));
                As[c4 + 0][mm] = v.x; As[c4 + 1][mm] = v.y;
                As[c4 + 2][mm] = v.z; As[c4 + 3][mm] = v.w;
            }
        }
        {
            // Bs[kk][nn] = B[(k0+kk)*N + n0+nn]
            const int kk = tid >> 5;
            const int n4 = (tid & 31) << 2;
            #pragma unroll
            for (int r = 0; r < 2; ++r) {
                const int kkk = kk + 8 * r;
                if (BBF16) {
                    const unsigned short* src = (const unsigned short*)Bv + (long)b * bBatch
                                                + (long)(k0 + kkk) * N + (n0 + n4);
                    ushort4 u = *(const ushort4*)src;
                    *(float4*)&Bs[kkk][n4] =
                        make_float4(bf2f(u.x), bf2f(u.y), bf2f(u.z), bf2f(u.w));
                } else {
                    const float* src = (const float*)Bv + (long)b * bBatch
                                       + (long)(k0 + kkk) * N + (n0 + n4);
                    *(float4*)&Bs[kkk][n4] = *(const float4*)src;
                }
            }
        }
        __syncthreads();
        #pragma unroll
        for (int kk = 0; kk < BK; ++kk) {
            float a[8], bb[8];
            *(float4*)&a[0]  = *(const float4*)&As[kk][(ty << 2)];
            *(float4*)&a[4]  = *(const float4*)&As[kk][64 + (ty << 2)];
            *(float4*)&bb[0] = *(const float4*)&Bs[kk][(tx << 2)];
            *(float4*)&bb[4] = *(const float4*)&Bs[kk][64 + (tx << 2)];
            #pragma unroll
            for (int i = 0; i < 8; ++i)
                #pragma unroll
                for (int j = 0; j < 8; ++j)
                    acc[i][j] = fmaf(a[i], bb[j], acc[i][j]);
        }
        __syncthreads();
    }

    // ---- epilogue ----
    float csr[8];
    if (MODE == M_XR) {
        #pragma unroll
        for (int j = 0; j < 8; ++j) {
            const int nj = n0 + ((j < 4) ? (tx << 2) + j : 64 + (tx << 2) + (j - 4));
            csr[j] = 1.0f / (1e-9f + colsum[(long)b * N + nj]);
        }
    }
    #pragma unroll
    for (int i = 0; i < 8; ++i) {
        const int mloc = (i < 4) ? (ty << 2) + i : 64 + (ty << 2) + (i - 4);
        const int mi = m0 + mloc;
        if (mi >= M) continue;
        float rowBias = 0.f, sc = 0.f, sh = 0.f;
        if (MODE == M_BIAS || MODE == M_TOUT) rowBias = bias[mi];
        if (MODE == M_BNRELU || MODE == M_TOUT) {
            const float g = bng[mi], be = bnb[mi], mu = bnm[mi], va = bnv[mi];
            sc = g * rsqrtf(va + 1e-3f);
            sh = be - mu * sc;
        }
        #pragma unroll
        for (int jh = 0; jh < 2; ++jh) {
            const int nj0 = n0 + 64 * jh + (tx << 2);
            float4 hv = make_float4(0.f, 0.f, 0.f, 0.f);
            if (MODE == M_XR || MODE == M_TOUT)
                hv = *(const float4*)(Haux + (long)b * hBatch + (long)mi * N + nj0);
            float o[4];
            #pragma unroll
            for (int jj = 0; jj < 4; ++jj) {
                float v = acc[i][jh * 4 + jj];
                if (MODE == M_BIAS)        v += rowBias;
                else if (MODE == M_BNRELU) v = fmaxf(fmaf(v, sc, sh), 0.f);
                else if (MODE == M_XR)     v = (&hv.x)[jj] - v * csr[jh * 4 + jj];
                else if (MODE == M_TOUT) {
                    const float t = v + rowBias;
                    v = (&hv.x)[jj] + fmaxf(fmaf(t, sc, sh), 0.f);
                }
                o[jj] = v;
            }
            if (MODE == M_EOUT) {
                ushort4 u;
                u.x = f2bf(o[0]); u.y = f2bf(o[1]); u.z = f2bf(o[2]); u.w = f2bf(o[3]);
                *(ushort4*)((unsigned short*)Yv + (long)b * yBatch + (long)mi * N + nj0) = u;
            } else {
                *(float4*)((float*)Yv + (long)b * yBatch + (long)mi * N + nj0) =
                    make_float4(o[0], o[1], o[2], o[3]);
            }
        }
    }
}

// In-place row softmax on bf16 matrix: one block per (batch,row), 256 threads, 8 elems/thread.
__global__ __launch_bounds__(256)
void softmax_kernel(unsigned short* __restrict__ E, int N)
{
    const int t = threadIdx.x;
    unsigned short* row = E + ((long)blockIdx.y * N + blockIdx.x) * N;
    ushort4 u0 = *(const ushort4*)(row + t * 8);
    ushort4 u1 = *(const ushort4*)(row + t * 8 + 4);
    float v[8] = { bf2f(u0.x), bf2f(u0.y), bf2f(u0.z), bf2f(u0.w),
                   bf2f(u1.x), bf2f(u1.y), bf2f(u1.z), bf2f(u1.w) };
    float mx = v[0];
    #pragma unroll
    for (int i = 1; i < 8; ++i) mx = fmaxf(mx, v[i]);
    #pragma unroll
    for (int off = 32; off; off >>= 1) mx = fmaxf(mx, __shfl_xor(mx, off));
    __shared__ float red[8];
    if ((t & 63) == 0) red[t >> 6] = mx;
    __syncthreads();
    mx = fmaxf(fmaxf(red[0], red[1]), fmaxf(red[2], red[3]));
    float s = 0.f;
    #pragma unroll
    for (int i = 0; i < 8; ++i) { v[i] = __expf(v[i] - mx); s += v[i]; }
    #pragma unroll
    for (int off = 32; off; off >>= 1) s += __shfl_xor(s, off);
    if ((t & 63) == 0) red[4 + (t >> 6)] = s;
    __syncthreads();
    s = (red[4] + red[5]) + (red[6] + red[7]);
    const float inv = 1.0f / s;
    #pragma unroll
    for (int i = 0; i < 8; ++i) v[i] *= inv;
    u0.x = f2bf(v[0]); u0.y = f2bf(v[1]); u0.z = f2bf(v[2]); u0.w = f2bf(v[3]);
    u1.x = f2bf(v[4]); u1.y = f2bf(v[5]); u1.z = f2bf(v[6]); u1.w = f2bf(v[7]);
    *(ushort4*)(row + t * 8) = u0;
    *(ushort4*)(row + t * 8 + 4) = u1;
}

// colsum[b,m] = sum_n attn[b,n,m]; grid (rowChunks, B), thread t owns 8 contiguous columns.
__global__ __launch_bounds__(256)
void colsum_kernel(const unsigned short* __restrict__ attn, float* __restrict__ cs,
                   int N, int rowsPer)
{
    const int b = blockIdx.y;
    const long base = ((long)b * N + (long)blockIdx.x * rowsPer) * N + threadIdx.x * 8;
    float s[8] = {0, 0, 0, 0, 0, 0, 0, 0};
    for (int r = 0; r < rowsPer; ++r) {
        ushort4 u0 = *(const ushort4*)(attn + base + (long)r * N);
        ushort4 u1 = *(const ushort4*)(attn + base + (long)r * N + 4);
        s[0] += bf2f(u0.x); s[1] += bf2f(u0.y); s[2] += bf2f(u0.z); s[3] += bf2f(u0.w);
        s[4] += bf2f(u1.x); s[5] += bf2f(u1.y); s[6] += bf2f(u1.z); s[7] += bf2f(u1.w);
    }
    float* o = cs + (long)b * N + threadIdx.x * 8;
    #pragma unroll
    for (int i = 0; i < 8; ++i) atomicAdd(o + i, s[i]);
}

extern "C" void kernel_launch(void* const* d_in, const int* in_sizes, int n_in,
                              void* d_out, int out_size, void* d_ws, size_t ws_size,
                              hipStream_t stream)
{
    const float* x    = (const float*)d_in[0];
    const float* c1w  = (const float*)d_in[1];
    const float* c2w  = (const float*)d_in[2];
    const float* bn1g = (const float*)d_in[3], *bn1b = (const float*)d_in[4];
    const float* bn1m = (const float*)d_in[5], *bn1v = (const float*)d_in[6];
    const float* bn2g = (const float*)d_in[7], *bn2b = (const float*)d_in[8];
    const float* bn2m = (const float*)d_in[9], *bn2v = (const float*)d_in[10];
    const float* qkw  = (const float*)d_in[11];
    const float* vw   = (const float*)d_in[12];
    const float* vb   = (const float*)d_in[13];
    const float* tw   = (const float*)d_in[14];
    const float* tb   = (const float*)d_in[15];
    const float* sag  = (const float*)d_in[16];
    const float* sab  = (const float*)d_in[17];
    const float* sam  = (const float*)d_in[18];
    const float* sav  = (const float*)d_in[19];
    // d_in[20] = flag, unused by the reference.
    float* out = (float*)d_out;

    // Workspace layout (bytes): hA/hB/hC 32MB each, q 8MB, colsum 128KB, E(bf16) 128MB
    // total = 243,400,704 bytes.
    char* ws = (char*)d_ws;
    const long HB = (long)Bn * Cc * Nn * 4;            // 33,554,432
    float* hA = (float*)(ws);
    float* hB = (float*)(ws + HB);
    float* hC = (float*)(ws + 2 * HB);
    float* qb = (float*)(ws + 3 * HB);
    float* cs = (float*)(ws + 3 * HB + (long)Bn * C4 * Nn * 4);
    unsigned short* E = (unsigned short*)(ws + 3 * HB + (long)Bn * C4 * Nn * 4
                                          + (long)Bn * Nn * 4);

    const long sCN  = (long)Cc * Nn;     // 524288
    const long s4CN = 4 * sCN;
    const long sQ   = (long)C4 * Nn;
    const long sE   = (long)Nn * Nn;

    dim3 blk(256);
    dim3 gConv(Nn / 128, 2, Bn);   // M=256
    dim3 gQ(Nn / 128, 1, Bn);      // M=64
    dim3 gE(Nn / 128, Nn / 128, Bn);

    // conv1: hA = relu(bn1(c1w @ x))
    gemm_kernel<M_BNRELU, false, false><<<gConv, blk, 0, stream>>>(
        c1w, 0, Cc, x, sCN, hA, sCN, nullptr, 0,
        nullptr, bn1g, bn1b, bn1m, bn1v, nullptr, Cc, Nn, Cc);
    // conv2: hB = relu(bn2(c2w @ hA))
    gemm_kernel<M_BNRELU, false, false><<<gConv, blk, 0, stream>>>(
        c2w, 0, Cc, hA, sCN, hB, sCN, nullptr, 0,
        nullptr, bn2g, bn2b, bn2m, bn2v, nullptr, Cc, Nn, Cc);

    for (int i = 0; i < 4; ++i) {
        const float* hin; long hinB;
        if (i == 0) { hin = hB; hinB = sCN; }
        else        { hin = out + (long)(i - 1) * sCN; hinB = s4CN; }

        // q = qk_w @ hin    [B,64,N]
        gemm_kernel<M_NONE, false, false><<<gQ, blk, 0, stream>>>(
            qkw + (long)i * C4 * Cc, 0, Cc, hin, hinB, qb, sQ, nullptr, 0,
            nullptr, nullptr, nullptr, nullptr, nullptr, nullptr, C4, Nn, Cc);
        // E = q^T q  (bf16 logits)
        gemm_kernel<M_EOUT, true, false><<<gE, blk, 0, stream>>>(
            qb, sQ, Nn, qb, sQ, E, sE, nullptr, 0,
            nullptr, nullptr, nullptr, nullptr, nullptr, nullptr, Nn, Nn, C4);
        // row softmax in place
        softmax_kernel<<<dim3(Nn, Bn), blk, 0, stream>>>(E, Nn);
        // column sums of softmaxed attn
        hipMemsetAsync(cs, 0, (long)Bn * Nn * 4, stream);
        colsum_kernel<<<dim3(32, Bn), blk, 0, stream>>>(E, cs, Nn, Nn / 32);
        // xv = v_w @ hin + v_b   -> hA
        gemm_kernel<M_BIAS, false, false><<<gConv, blk, 0, stream>>>(
            vw + (long)i * Cc * Cc, 0, Cc, hin, hinB, hA, sCN, nullptr, 0,
            vb + i * Cc, nullptr, nullptr, nullptr, nullptr, nullptr, Cc, Nn, Cc);
        // d = hin - (xv @ attn)/(1e-9+colsum)   -> hC
        gemm_kernel<M_XR, false, true><<<gConv, blk, 0, stream>>>(
            hA, sCN, Nn, E, sE, hC, sCN, hin, hinB,
            nullptr, nullptr, nullptr, nullptr, nullptr, cs, Cc, Nn, Nn);
        // out_i = hin + relu(bn(t_w @ d + t_b))  -> d_out slice i
        gemm_kernel<M_TOUT, false, false><<<gConv, blk, 0, stream>>>(
            tw + (long)i * Cc * Cc, 0, Cc, hC, sCN, out + (long)i * sCN, s4CN, hin, hinB,
            tb + i * Cc, sag + i * Cc, sab + i * Cc, sam + i * Cc, sav + i * Cc,
            nullptr, Cc, Nn, Cc);
    }
}

// Round 3
// 1050.174 us; speedup vs baseline: 3.1660x; 3.1660x over previous
//
#include <hip/hip_runtime.h>
#include <hip/hip_bf16.h>
#include <hip/hip_fp16.h>

// Problem constants: B=16, C=256, N=2048, NUM_SA=4
static constexpr int Bn = 16;
static constexpr int Cc = 256;
static constexpr int Nn = 2048;
static constexpr int C4 = 64;

typedef _Float16 half_t;
typedef __attribute__((ext_vector_type(8))) _Float16 half8;
typedef __attribute__((ext_vector_type(4))) _Float16 half4;
typedef __attribute__((ext_vector_type(8))) short short8;
typedef __attribute__((ext_vector_type(4))) float float4v;

#define DEVI __device__ __forceinline__

DEVI float bf2f(unsigned short u) { return __uint_as_float(((unsigned)u) << 16); }
DEVI unsigned short f2bf(float f) {
    unsigned x = __float_as_uint(f);
    x += 0x7fffu + ((x >> 16) & 1u);   // RNE
    return (unsigned short)(x >> 16);
}

// async global->LDS, 16B per lane. LDS dest = wave-uniform base + lane*16.
DEVI void gload16(const void* g, void* l) {
    __builtin_amdgcn_global_load_lds(
        (const __attribute__((address_space(1))) unsigned int*)g,
        (__attribute__((address_space(3))) unsigned int*)l, 16, 0, 0);
}

enum { EPI_RAW = 0, EPI_H = 1, EPI_XV = 2, EPI_XR = 3, EPI_T = 4 };

// Canonical MFMA GEMM: Y[j][i] = epi( sum_k A[i*K+k] * B[j*K+k] )
//   i = MFMA row dim (BM per block), j = MFMA col dim (BN per block).
//   Both A and B row-major contiguous in k (16-bit elements; fp16 or bf16 per BF16IN).
// Epilogues:
//   EPI_RAW : fp16 store                          (q GEMM, E GEMM)
//   EPI_H   : relu(bn(acc)) by channel i, fp16    (conv1/conv2 -> h[n][c])
//   EPI_XV  : acc + bias[j]; fp16 or bf16 (BF16OUT) (xv -> [c][n])
//   EPI_XR  : h[j][i] - acc/(1e-9+colsum[j]), f16 (d = h - x_r_norm -> [m][c])
//   EPI_T   : h + relu(bn(acc+tb[j])) fp32 out; optional fp16 h_next scatter
template<int MODE, int BM, int BN, int WI, int WJ, bool BF16IN, bool BF16OUT>
__global__ __launch_bounds__(256)
void mgemm(const half_t* __restrict__ A, long aB,
           const half_t* __restrict__ Bm, long bB,
           void* __restrict__ Yv, long yB, int ldy,
           const half_t* __restrict__ Haux, long hB,
           half_t* __restrict__ hNext, long hnB,
           const float* __restrict__ bias,
           const float* __restrict__ bng, const float* __restrict__ bnb,
           const float* __restrict__ bnm, const float* __restrict__ bnv,
           const float* __restrict__ colsum,
           int K)
{
    __shared__ __align__(16) half_t Als[2][BM][32];
    __shared__ __align__(16) half_t Bls[2][BN][32];

    const int tid  = threadIdx.x;
    const int w    = tid >> 6;
    const int lane = tid & 63;
    const int wi   = (WI == 1) ? 0 : (w & (WI - 1));
    const int wj   = (WI == 1) ? w : (w >> 1);
    const int quad = lane >> 4, m16 = lane & 15;
    const int lr   = lane >> 2, lc = lane & 3;       // staging: row-in-issue, 16B chunk
    const int b    = blockIdx.z;
    const int j0   = blockIdx.x * BN;
    const int i0   = blockIdx.y * BM;

    const half_t* Ab = A + (size_t)b * aB;
    const half_t* Bb = Bm + (size_t)b * bB;

    float4v acc[4][4];
    #pragma unroll
    for (int i = 0; i < 4; ++i)
        #pragma unroll
        for (int j = 0; j < 4; ++j) acc[i][j] = (float4v)0.f;

    for (int k0 = 0; k0 < K; k0 += 64) {
        #pragma unroll
        for (int s = 0; s < 2; ++s) {
            const int kk = k0 + s * 32 + lc * 8;
            #pragma unroll
            for (int t = 0; t < BM / 64; ++t) {
                const int row = (t * 4 + w) * 16;    // wave w stages rows [row, row+16)
                gload16(Ab + (size_t)(i0 + row + lr) * K + kk, &Als[s][row][0]);
            }
            #pragma unroll
            for (int t = 0; t < BN / 64; ++t) {
                const int row = (t * 4 + w) * 16;
                gload16(Bb + (size_t)(j0 + row + lr) * K + kk, &Bls[s][row][0]);
            }
        }
        __syncthreads();   // drains vmcnt (global_load_lds) + barrier
        #pragma unroll
        for (int s = 0; s < 2; ++s) {
            if constexpr (!BF16IN) {
                half8 af[4], bf[4];
                #pragma unroll
                for (int t = 0; t < 4; ++t)
                    af[t] = *(const half8*)&Als[s][wi * 64 + t * 16 + m16][quad * 8];
                #pragma unroll
                for (int t = 0; t < 4; ++t)
                    bf[t] = *(const half8*)&Bls[s][wj * 64 + t * 16 + m16][quad * 8];
                #pragma unroll
                for (int ti = 0; ti < 4; ++ti)
                    #pragma unroll
                    for (int tj = 0; tj < 4; ++tj)
                        acc[ti][tj] = __builtin_amdgcn_mfma_f32_16x16x32_f16(
                            af[ti], bf[tj], acc[ti][tj], 0, 0, 0);
            } else {
                short8 af[4], bf[4];
                #pragma unroll
                for (int t = 0; t < 4; ++t)
                    af[t] = *(const short8*)&Als[s][wi * 64 + t * 16 + m16][quad * 8];
                #pragma unroll
                for (int t = 0; t < 4; ++t)
                    bf[t] = *(const short8*)&Bls[s][wj * 64 + t * 16 + m16][quad * 8];
                #pragma unroll
                for (int ti = 0; ti < 4; ++ti)
                    #pragma unroll
                    for (int tj = 0; tj < 4; ++tj)
                        acc[ti][tj] = __builtin_amdgcn_mfma_f32_16x16x32_bf16(
                            af[ti], bf[tj], acc[ti][tj], 0, 0, 0);
            }
        }
        __syncthreads();   // protect LDS before next stage
    }

    // ---- epilogue ----  per lane: j fixed (col), 4 consecutive i (rows)
    #pragma unroll
    for (int ti = 0; ti < 4; ++ti) {
        const int il = i0 + wi * 64 + ti * 16 + quad * 4;
        #pragma unroll
        for (int tj = 0; tj < 4; ++tj) {
            const int jl = j0 + wj * 64 + tj * 16 + m16;
            float4v v = acc[ti][tj];
            if (MODE == EPI_RAW) {
                half4 o;
                #pragma unroll
                for (int r = 0; r < 4; ++r) o[r] = (half_t)v[r];
                *(half4*)((half_t*)Yv + (size_t)b * yB + (size_t)jl * ldy + il) = o;
            } else if (MODE == EPI_H) {
                half4 o;
                #pragma unroll
                for (int r = 0; r < 4; ++r) {
                    const float sc = bng[il + r] * rsqrtf(bnv[il + r] + 1e-3f);
                    const float sh = bnb[il + r] - bnm[il + r] * sc;
                    o[r] = (half_t)fmaxf(fmaf(v[r], sc, sh), 0.f);
                }
                *(half4*)((half_t*)Yv + (size_t)b * yB + (size_t)jl * ldy + il) = o;
            } else if (MODE == EPI_XV) {
                const float bj = bias[jl];
                if (BF16OUT) {
                    ushort4 o;
                    o.x = f2bf(v[0] + bj); o.y = f2bf(v[1] + bj);
                    o.z = f2bf(v[2] + bj); o.w = f2bf(v[3] + bj);
                    *(ushort4*)((unsigned short*)Yv + (size_t)b * yB + (size_t)jl * ldy + il) = o;
                } else {
                    half4 o;
                    #pragma unroll
                    for (int r = 0; r < 4; ++r) o[r] = (half_t)(v[r] + bj);
                    *(half4*)((half_t*)Yv + (size_t)b * yB + (size_t)jl * ldy + il) = o;
                }
            } else if (MODE == EPI_XR) {
                const float csr = 1.0f / (1e-9f + colsum[b * Nn + jl]);
                const half4 hv = *(const half4*)(Haux + (size_t)b * hB + (size_t)jl * Cc + il);
                half4 o;
                #pragma unroll
                for (int r = 0; r < 4; ++r)
                    o[r] = (half_t)((float)hv[r] - v[r] * csr);
                *(half4*)((half_t*)Yv + (size_t)b * yB + (size_t)jl * ldy + il) = o;
            } else {   // EPI_T
                const float tb2 = bias[jl];
                const float sc  = bng[jl] * rsqrtf(bnv[jl] + 1e-3f);
                const float sh  = bnb[jl] - bnm[jl] * sc;
                float4v o;
                #pragma unroll
                for (int r = 0; r < 4; ++r) {
                    const float t2  = v[r] + tb2;
                    const float rel = fmaxf(fmaf(t2, sc, sh), 0.f);
                    const float hv  = (float)Haux[(size_t)b * hB + (size_t)(il + r) * Cc + jl];
                    const float ov  = hv + rel;
                    o[r] = ov;
                    if (hNext)
                        hNext[(size_t)b * hnB + (size_t)(il + r) * Cc + jl] = (half_t)ov;
                }
                *(float4v*)((float*)Yv + (size_t)b * yB + (size_t)jl * ldy + il) = o;
            }
        }
    }
}

// Row stats of E (fp16 [m][n]): mx[r] = max_n E[r][n], inv[r] = 1/sum_n exp(E-mx).
// By symmetry of E = q q^T these are also the column stats.
__global__ __launch_bounds__(256)
void rowstats(const half_t* __restrict__ E, float* __restrict__ mx, float* __restrict__ inv)
{
    const int r = blockIdx.x, b = blockIdx.y, t = threadIdx.x;
    const half_t* row = E + ((size_t)b * Nn + r) * Nn;
    half8 e = *(const half8*)(row + t * 8);
    float v[8];
    #pragma unroll
    for (int i = 0; i < 8; ++i) v[i] = (float)e[i];
    float m = v[0];
    #pragma unroll
    for (int i = 1; i < 8; ++i) m = fmaxf(m, v[i]);
    #pragma unroll
    for (int off = 32; off; off >>= 1) m = fmaxf(m, __shfl_xor(m, off));
    __shared__ float red[8];
    if ((t & 63) == 0) red[t >> 6] = m;
    __syncthreads();
    m = fmaxf(fmaxf(red[0], red[1]), fmaxf(red[2], red[3]));
    float s = 0.f;
    #pragma unroll
    for (int i = 0; i < 8; ++i) s += __expf(v[i] - m);
    #pragma unroll
    for (int off = 32; off; off >>= 1) s += __shfl_xor(s, off);
    if ((t & 63) == 0) red[4 + (t >> 6)] = s;
    __syncthreads();
    if (t == 0) {
        s = (red[4] + red[5]) + (red[6] + red[7]);
        mx[b * Nn + r]  = m;
        inv[b * Nn + r] = 1.0f / s;
    }
}

// In-place: fp16 logits E[m][n] -> BF16 attn_T[m][n] = exp(E[m][n]-mx[n])*inv[n];
// colsum[m] = row-sum of the ROUNDED bf16 values (numerator/denominator consistency).
__global__ __launch_bounds__(256)
void attnnorm(half_t* __restrict__ Ebuf, const float* __restrict__ mx,
              const float* __restrict__ inv, float* __restrict__ cs)
{
    const int m = blockIdx.x, b = blockIdx.y, t = threadIdx.x;
    half_t* row = Ebuf + ((size_t)b * Nn + m) * Nn;
    const float* mxb = mx + (size_t)b * Nn;
    const float* ivb = inv + (size_t)b * Nn;
    half8 e = *(const half8*)(row + t * 8);
    float4v m0 = *(const float4v*)(mxb + t * 8);
    float4v m1 = *(const float4v*)(mxb + t * 8 + 4);
    float4v i0 = *(const float4v*)(ivb + t * 8);
    float4v i1 = *(const float4v*)(ivb + t * 8 + 4);
    float s = 0.f;
    unsigned short ob[8];
    #pragma unroll
    for (int i = 0; i < 8; ++i) {
        const float mm = (i < 4) ? m0[i] : m1[i - 4];
        const float ii = (i < 4) ? i0[i] : i1[i - 4];
        const float a  = __expf((float)e[i] - mm) * ii;
        const unsigned short ab = f2bf(a);
        ob[i] = ab;
        s += bf2f(ab);
    }
    ushort4 u0 = make_ushort4(ob[0], ob[1], ob[2], ob[3]);
    ushort4 u1 = make_ushort4(ob[4], ob[5], ob[6], ob[7]);
    *(ushort4*)((unsigned short*)row + t * 8) = u0;
    *(ushort4*)((unsigned short*)row + t * 8 + 4) = u1;
    #pragma unroll
    for (int off = 32; off; off >>= 1) s += __shfl_xor(s, off);
    __shared__ float red[4];
    if ((t & 63) == 0) red[t >> 6] = s;
    __syncthreads();
    if (t == 0) cs[(size_t)b * Nn + m] = (red[0] + red[1]) + (red[2] + red[3]);
}

// x [B,C,N] fp32 -> xT [B,N,C] fp16 (transpose + cast), 32x32 LDS tiles.
__global__ __launch_bounds__(256)
void xpose_cast(const float* __restrict__ x, half_t* __restrict__ xT)
{
    __shared__ half_t tile[32][33];
    const int tx = threadIdx.x & 31, ty = threadIdx.x >> 5;
    const int n0 = blockIdx.x * 32, c0 = blockIdx.y * 32, b = blockIdx.z;
    #pragma unroll
    for (int r = 0; r < 4; ++r)
        tile[ty * 4 + r][tx] =
            (half_t)x[((size_t)b * Cc + c0 + ty * 4 + r) * Nn + n0 + tx];
    __syncthreads();
    #pragma unroll
    for (int r = 0; r < 4; ++r)
        xT[((size_t)b * Nn + n0 + ty * 4 + r) * Cc + c0 + tx] = tile[tx][ty * 4 + r];
}

// bulk fp32 -> fp16 cast (n multiple of 1024)
__global__ __launch_bounds__(256)
void castk(const float* __restrict__ s, half_t* __restrict__ d, int n)
{
    const int i = (blockIdx.x * 256 + threadIdx.x) * 4;
    if (i < n) {
        const float4v v = *(const float4v*)(s + i);
        half4 o;
        #pragma unroll
        for (int r = 0; r < 4; ++r) o[r] = (half_t)v[r];
        *(half4*)(d + i) = o;
    }
}

extern "C" void kernel_launch(void* const* d_in, const int* in_sizes, int n_in,
                              void* d_out, int out_size, void* d_ws, size_t ws_size,
                              hipStream_t stream)
{
    const float* x    = (const float*)d_in[0];
    const float* c1w  = (const float*)d_in[1];
    const float* c2w  = (const float*)d_in[2];
    const float* bn1g = (const float*)d_in[3], *bn1b = (const float*)d_in[4];
    const float* bn1m = (const float*)d_in[5], *bn1v = (const float*)d_in[6];
    const float* bn2g = (const float*)d_in[7], *bn2b = (const float*)d_in[8];
    const float* bn2m = (const float*)d_in[9], *bn2v = (const float*)d_in[10];
    const float* qkw  = (const float*)d_in[11];
    const float* vw   = (const float*)d_in[12];
    const float* vb   = (const float*)d_in[13];
    const float* tw   = (const float*)d_in[14];
    const float* tb   = (const float*)d_in[15];
    const float* sag  = (const float*)d_in[16];
    const float* sab  = (const float*)d_in[17];
    const float* sam  = (const float*)d_in[18];
    const float* sav  = (const float*)d_in[19];
    float* out = (float*)d_out;

    // ---- workspace layout (16-bit unless noted), ~214 MB total ----
    char* ws = (char*)d_ws;
    const size_t HSZ = (size_t)Bn * Nn * Cc * 2;            // 16 MB
    half_t* xT   = (half_t*)(ws);
    half_t* hA   = (half_t*)(ws + HSZ);
    half_t* hBuf = (half_t*)(ws + 2 * HSZ);
    half_t* q_s  = (half_t*)(ws + 3 * HSZ);                 // 4 MB
    half_t* xv_s = (half_t*)(ws + 3 * HSZ + 4194304);       // bf16 payload
    half_t* d_s  = (half_t*)(ws + 4 * HSZ + 4194304);
    float*  mx   = (float*) (ws + 5 * HSZ + 4194304);       // 128 KB
    float*  inv  = (float*) (ws + 5 * HSZ + 4325376);
    float*  cs   = (float*) (ws + 5 * HSZ + 4456448);
    half_t* wc1  = (half_t*)(ws + 5 * HSZ + 4587520);       // casted weights
    half_t* wc2  = wc1 + 65536;
    half_t* wqk  = wc2 + 65536;
    half_t* wv   = wqk + 65536;
    half_t* wt   = wv  + 262144;
    half_t* E    = (half_t*)(ws + 5 * HSZ + 4587520 + 1441792);  // 128 MB

    const long sNC = (long)Nn * Cc;       // 524288
    const long sNQ = (long)Nn * C4;       // 131072
    const long sEE = (long)Nn * Nn;       // 4194304

    dim3 blk(256);

    // weight casts
    castk<<<64,  blk, 0, stream>>>(c1w, wc1, 65536);
    castk<<<64,  blk, 0, stream>>>(c2w, wc2, 65536);
    castk<<<64,  blk, 0, stream>>>(qkw, wqk, 65536);
    castk<<<256, blk, 0, stream>>>(vw,  wv,  262144);
    castk<<<256, blk, 0, stream>>>(tw,  wt,  262144);
    // x -> xT fp16
    xpose_cast<<<dim3(Nn / 32, Cc / 32, Bn), blk, 0, stream>>>(x, xT);

    // conv1: h1[n][c] = relu(bn1(W1 @ x))   (i=c, j=n)
    mgemm<EPI_H, 128, 128, 2, 2, false, false><<<dim3(16, 2, Bn), blk, 0, stream>>>(
        wc1, 0, xT, sNC, hA, sNC, Cc, nullptr, 0, nullptr, 0,
        nullptr, bn1g, bn1b, bn1m, bn1v, nullptr, Cc);
    // conv2: h2[n][c]
    mgemm<EPI_H, 128, 128, 2, 2, false, false><<<dim3(16, 2, Bn), blk, 0, stream>>>(
        wc2, 0, hA, sNC, hBuf, sNC, Cc, nullptr, 0, nullptr, 0,
        nullptr, bn2g, bn2b, bn2m, bn2v, nullptr, Cc);

    half_t* hcur = hBuf;
    half_t* hnxt = hA;
    for (int L = 0; L < 4; ++L) {
        // q[n][cq] (i=cq M=64, j=n)
        mgemm<EPI_RAW, 64, 256, 1, 4, false, false><<<dim3(8, 1, Bn), blk, 0, stream>>>(
            wqk + (long)L * C4 * Cc, 0, hcur, sNC, q_s, sNQ, C4,
            nullptr, 0, nullptr, 0,
            nullptr, nullptr, nullptr, nullptr, nullptr, nullptr, Cc);
        // E[m][n] = q_s[n]·q_s[m]  (i=n, j=m, K=64), fp16 logits
        mgemm<EPI_RAW, 128, 128, 2, 2, false, false><<<dim3(16, 16, Bn), blk, 0, stream>>>(
            q_s, sNQ, q_s, sNQ, E, sEE, Nn,
            nullptr, 0, nullptr, 0,
            nullptr, nullptr, nullptr, nullptr, nullptr, nullptr, C4);
        rowstats<<<dim3(Nn, Bn), blk, 0, stream>>>(E, mx, inv);
        attnnorm<<<dim3(Nn, Bn), blk, 0, stream>>>(E, mx, inv, cs);  // -> bf16 attn
        // xv[c][n] = vw @ h + vb  (i=n, j=c), bf16 out
        mgemm<EPI_XV, 128, 128, 2, 2, false, true><<<dim3(2, 16, Bn), blk, 0, stream>>>(
            hcur, sNC, wv + (long)L * Cc * Cc, 0, xv_s, (long)Cc * Nn, Nn,
            nullptr, 0, nullptr, 0,
            vb + L * Cc, nullptr, nullptr, nullptr, nullptr, nullptr, Cc);
        // d[m][c] = h[m][c] - (xv @ attn)/(1e-9+colsum)  (i=c, j=m, K=2048), bf16 MFMA
        mgemm<EPI_XR, 128, 128, 2, 2, true, false><<<dim3(16, 2, Bn), blk, 0, stream>>>(
            xv_s, (long)Cc * Nn, E, sEE, d_s, sNC, Cc,
            hcur, sNC, nullptr, 0,
            nullptr, nullptr, nullptr, nullptr, nullptr, cs, Nn);
        // out_L[c][n] = h + relu(bn(tw @ d + tb)); also h_next[n][c] fp16
        mgemm<EPI_T, 128, 128, 2, 2, false, false><<<dim3(2, 16, Bn), blk, 0, stream>>>(
            d_s, sNC, wt + (long)L * Cc * Cc, 0,
            out + (long)L * Cc * Nn, (long)4 * Cc * Nn, Nn,
            hcur, sNC, (L < 3) ? hnxt : nullptr, sNC,
            tb + L * Cc, sag + L * Cc, sab + L * Cc, sam + L * Cc, sav + L * Cc,
            nullptr, Cc);
        half_t* tmp = hcur; hcur = hnxt; hnxt = tmp;
    }
}